// Round 9
// baseline (114.945 us; speedup 1.0000x reference)
//
#include <hip/hip_runtime.h>

// CorrelationCost (tfa): out[b, dy*9+dx, y, x] =
//   (1/128) * sum_c prv[b,c,y,x] * nxt[b,c,y+dy-4,x+dx-4], zero-padded.
// B=4, C=128, H=128, W=256 -> out [4, 81, 128, 256] fp32.
//
// R9: MFMA Gram-band formulation. For a 16-wide x-tile, the 9-dx band is a
// band of P^T N (K = channels). Two mfma_f32_16x16x32_f16 per (y,dy,xsub)
// cover dx in 0..8. Block = (b, 2 y-rows, 64 x), all 81 displacements
// internal -> nxt rows loaded once per block (10 rows). 8 waves =
// 4 xsub x 2 s-groups (s = y+dy, s = g mod 2 interleaved by 4 -> balanced
// 9 (y,dy) pairs / 18 MFMAs per wave per 32-ch chunk; B-frags shared
// across pairs with equal s). f16 inputs via cvt_pkrtz (fp32 accumulate).

#define SR 4
#define ND 9
#define BB 4
#define CC 128
#define HH 128
#define WW 256
#define HW (HH * WW)

typedef __fp16 h2 __attribute__((ext_vector_type(2)));
typedef __fp16 h8 __attribute__((ext_vector_type(8)));
typedef float f4v __attribute__((ext_vector_type(4)));

static __device__ __forceinline__ h2 pk(float lo, float hi) {
    return __builtin_amdgcn_cvt_pkrtz(lo, hi);
}
static __device__ __forceinline__ unsigned as_u32(h2 h) {
    union { h2 h; unsigned u; } v; v.h = h; return v.u;
}
static __device__ __forceinline__ h8 as_h8(uint4 u) {
    union { uint4 u; h8 h; } v; v.u = u; return v.h;
}
// cp-block swizzle: spreads the 20-u32 x-stride across banks for both
// b128 frag reads (2-way max) and x-major b32 staging writes (2-way max).
static __device__ __forceinline__ int swz(int x) { return (x ^ (x >> 2)) & 3; }

// LDS u32 index for logical (x, cp) with row base rb (= x-row * 20).
#define CPOFF(cp, x) ((((cp) >> 2) ^ swz(x)) << 2 | ((cp) & 3))

template <int G>
__device__ __forceinline__ void chunk_compute(
    const unsigned* Pl, const unsigned* Nl,
    int Xloc, int li, int fro, f4v* d1, f4v* d2)
{
    const h8 a0 = as_h8(*(const uint4*)&Pl[(Xloc + li) * 20 + fro]);
    const h8 a1 = as_h8(*(const uint4*)&Pl[(64 + Xloc + li) * 20 + fro]);
    int p = 0;
    #pragma unroll
    for (int si = 0; si < 5; ++si) {
        const int s = G + 2 * si;
        const h8 b1 = as_h8(*(const uint4*)&Nl[(s * 80 + Xloc + li) * 20 + fro]);
        const h8 b2 = as_h8(*(const uint4*)&Nl[(s * 80 + Xloc + 16 + li) * 20 + fro]);
        const int ylo = (s - 8) > 0 ? (s - 8) : 0;
        const int yhi = s < 1 ? s : 1;
        #pragma unroll
        for (int y = ylo; y <= yhi; ++y) {
            const h8 a = (y == 0) ? a0 : a1;
            d1[p] = __builtin_amdgcn_mfma_f32_16x16x32_f16(a, b1, d1[p], 0, 0, 0);
            d2[p] = __builtin_amdgcn_mfma_f32_16x16x32_f16(a, b2, d2[p], 0, 0, 0);
            ++p;
        }
    }
}

template <int G>
__device__ __forceinline__ void epilogue(
    float* __restrict__ out, const f4v* d1, const f4v* d2,
    int b, int y0, int x0, int Xloc, int li, int hi)
{
    const float invc = 1.0f / 128.0f;
    int p = 0;
    #pragma unroll
    for (int si = 0; si < 5; ++si) {
        const int s = G + 2 * si;
        const int ylo = (s - 8) > 0 ? (s - 8) : 0;
        const int yhi = s < 1 ? s : 1;
        const bool yok = ((unsigned)(y0 + s - 4) < (unsigned)HH);
        #pragma unroll
        for (int y = ylo; y <= yhi; ++y) {
            const int dy = s - y;
            float* base = out + ((size_t)(b * 81 + dy * 9) * HH + (y0 + y)) * WW;
            #pragma unroll
            for (int r = 0; r < 4; ++r) {
                const int xo  = x0 + Xloc + (hi << 2) + r;
                const int dx1 = li - (hi << 2) - r - 4;
                const int dx2 = dx1 + 16;
                const float v1 = yok ? d1[p][r] * invc : 0.0f;
                const float v2 = yok ? d2[p][r] * invc : 0.0f;
                if ((unsigned)dx1 < 9u) base[(size_t)dx1 * HW + xo] = v1;
                if ((unsigned)dx2 < 9u) base[(size_t)dx2 * HW + xo] = v2;
            }
            ++p;
        }
    }
}

__global__ __launch_bounds__(512, 4) void costvol_kernel(
    const float* __restrict__ prv,
    const float* __restrict__ nxt,
    float* __restrict__ out)
{
    // [x-row][20 u32] layouts: P: 2y x 64x; N: 10 rows x 80x. 74.2 KB total.
    __shared__ unsigned Pl[2 * 64 * 20];
    __shared__ unsigned Nl[10 * 80 * 20];

    // XCD-chunked bijective swizzle (1024 % 8 == 0).
    const int nwg  = gridDim.x;
    const int cpx  = nwg >> 3;
    const int orig = blockIdx.x;
    const int wid  = (orig & 7) * cpx + (orig >> 3);

    const int xt = wid & 3;            // x-tile fastest: neighbors share N rows
    const int yt = (wid >> 2) & 63;
    const int b  = wid >> 8;
    const int x0 = xt << 6;
    const int y0 = yt << 1;

    const int tid  = threadIdx.x;
    const int wave = tid >> 6;
    const int lane = tid & 63;
    const int xs   = wave & 3;
    const int g    = wave >> 2;
    const int li   = lane & 15;
    const int hi   = lane >> 4;
    const int Xloc = xs << 4;
    const int swl  = (li ^ (li >> 2)) & 3;
    const int fro  = (hi ^ swl) << 2;   // frag-read cp offset (u32)

    f4v d1[9], d2[9];
    #pragma unroll
    for (int p = 0; p < 9; ++p) {
        d1[p] = (f4v){0.f, 0.f, 0.f, 0.f};
        d2[p] = (f4v){0.f, 0.f, 0.f, 0.f};
    }

    for (int ck = 0; ck < 4; ++ck) {
        const int c0 = ck << 5;
        __syncthreads();
        // ---- P stage: 2y x 64x x 16cp = 2048 u32 tasks (4 iters) ----
        #pragma unroll
        for (int it = 0; it < 4; ++it) {
            const int t  = tid + (it << 9);
            const int xr = t & 63;
            const int rc = t >> 6;       // 0..31
            const int y  = rc & 1;
            const int cp = rc >> 1;      // 0..15
            const float* s = prv + ((size_t)(b * CC + c0 + 2 * cp) * HH + (y0 + y)) * WW + (x0 + xr);
            Pl[((y << 6) + xr) * 20 + CPOFF(cp, xr)] = as_u32(pk(s[0], s[HW]));
        }
        // ---- N stage: 10 rows x 80x x 16cp = 12800 u32 tasks (25 iters) ----
        for (int it = 0; it < 25; ++it) {
            const int t   = tid + (it << 9);
            const int xr  = t % 80;
            const int rc  = t / 80;      // 0..159
            const int row = rc % 10;
            const int cp  = rc / 10;     // 0..15
            const int xg  = x0 - 8 + xr;
            int yr = y0 + row - 4;
            yr = yr < 0 ? 0 : (yr > HH - 1 ? HH - 1 : yr);
            const float* s = nxt + ((size_t)(b * CC + c0 + 2 * cp) * HH + yr) * WW + xg;
            float v0 = 0.f, v1 = 0.f;
            if ((unsigned)xg < (unsigned)WW) { v0 = s[0]; v1 = s[HW]; }
            Nl[(row * 80 + xr) * 20 + CPOFF(cp, xr)] = as_u32(pk(v0, v1));
        }
        __syncthreads();
        // ---- compute: 18 MFMAs / wave ----
        if (g == 0) chunk_compute<0>(Pl, Nl, Xloc, li, fro, d1, d2);
        else        chunk_compute<1>(Pl, Nl, Xloc, li, fro, d1, d2);
    }

    if (g == 0) epilogue<0>(out, d1, d2, b, y0, x0, Xloc, li, hi);
    else        epilogue<1>(out, d1, d2, b, y0, x0, Xloc, li, hi);
}

extern "C" void kernel_launch(void* const* d_in, const int* in_sizes, int n_in,
                              void* d_out, int out_size, void* d_ws, size_t ws_size,
                              hipStream_t stream) {
    const float* prv = (const float*)d_in[0];
    const float* nxt = (const float*)d_in[1];
    float* out = (float*)d_out;

    const int nblocks = BB * (HH / 2) * (WW / 64);  // 4 * 64 * 4 = 1024
    costvol_kernel<<<nblocks, 512, 0, stream>>>(prv, nxt, out);
}

// Round 10
// 66.112 us; speedup vs baseline: 1.7386x; 1.7386x over previous
//
#include <hip/hip_runtime.h>

// CorrelationCost (tfa): out[b, dy*9+dx, y, x] =
//   (1/128) * sum_c prv[b,c,y,x] * nxt[b,c,y+dy-4,x+dx-4], zero-padded.
// B=4, C=128, H=128, W=256 -> out [4, 81, 128, 256] fp32.
//
// R10: MFMA band-GEMM, staging fixed vs R9: pow2 task maps (no div/mod),
// float4-pair loads, stride-10 LDS (conflict-light b64 frags), double
// buffer, y4-tile (N redundancy 3x -> 368 MB traffic), LDS-transposed
// coalesced epilogue. mfma_f32_16x16x16f16, K=16ch/chunk, 8 chunks.
// D-layout (row=A-free=px, col=B-free=dx) confirmed by R9's pass.

#define SR 4
#define ND 9
#define BB 4
#define CC 128
#define HH 128
#define WW 256
#define HW (HH * WW)

#define YT 4          // y rows per block
#define XT 32         // x px per block
#define NR 12         // N rows staged: y0-4 .. y0+7
#define NW 48         // N px staged:  x0-8 .. x0+39
#define STR 10        // u32 stride per px (8 cp + 2 pad)
#define POFF 0
#define NOFF (YT * XT * STR)          // 1280
#define BUFSZ (NOFF + NR * NW * STR)  // 7040 u32 = 28160 B

typedef __fp16 h2 __attribute__((ext_vector_type(2)));
typedef __fp16 h4 __attribute__((ext_vector_type(4)));
typedef float f32x4 __attribute__((ext_vector_type(4)));

static __device__ __forceinline__ h2 pk(float lo, float hi) {
    return __builtin_amdgcn_cvt_pkrtz(lo, hi);
}
static __device__ __forceinline__ unsigned as_u32(h2 h) {
    union { h2 h; unsigned u; } v; v.h = h; return v.u;
}
static __device__ __forceinline__ h4 as_h4(uint2 u) {
    union { uint2 u; h4 h; } v; v.u = u; return v.h;
}

__global__ __launch_bounds__(512, 2) void costvol_kernel(
    const float* __restrict__ prv,
    const float* __restrict__ nxt,
    float* __restrict__ out)
{
    __shared__ unsigned lds[2][BUFSZ];   // 56320 B

    // XCD-chunked bijective swizzle (1024 % 8 == 0).
    const int nwg  = gridDim.x;
    const int cpx  = nwg >> 3;
    const int orig = blockIdx.x;
    const int wid  = (orig & 7) * cpx + (orig >> 3);

    // x-tile fastest: neighbor blocks share N rows in L2.
    const int xt = wid & 7;
    const int yt = (wid >> 3) & 31;
    const int b  = wid >> 8;
    const int x0 = xt << 5;
    const int y0 = yt << 2;

    const int tid  = threadIdx.x;
    const int w    = tid >> 6;
    const int lane = tid & 63;
    const int li   = lane & 15;
    const int kg   = lane >> 4;          // k-group 0..3
    const int koff = kg << 1;            // u32 offset of this lane's 4 halves

    const int y2 = w & 1;                // y-pair
    const int s  = (w >> 1) & 1;         // A subtile (16 px)
    const int g  = w >> 2;               // B tile parity
    const int ts = s + g;                // B tile index 0..2

    f32x4 acc0[ND], acc1[ND];
    #pragma unroll
    for (int dy = 0; dy < ND; ++dy) {
        acc0[dy] = (f32x4){0.f, 0.f, 0.f, 0.f};
        acc1[dy] = (f32x4){0.f, 0.f, 0.f, 0.f};
    }

    // ---- staging (all-pow2 decomposition) ----
    auto stage = [&](int buf, int ck) {
        const int c0 = ck << 4;
        unsigned* L = lds[buf];
        if (tid < 384) {
            // N: 12 rows x 12 quads x 8 cp = 1152 tasks, 384 thr x 3
            const int cp = tid & 7;
            const int u  = tid >> 3;         // 0..47
            const int q  = u >> 2;           // 0..11
            const int rb = u & 3;
            const int xg = x0 - 8 + (q << 2);
            const bool xok = (xg >= 0) && (xg + 3 < WW);
            const float* sp = nxt + ((size_t)(b * CC + c0 + 2 * cp) * HH) * WW + xg;
            #pragma unroll
            for (int it = 0; it < 3; ++it) {
                const int row = rb + (it << 2);          // 0..11
                const int rg  = y0 + row - SR;
                unsigned* d = L + NOFF + (row * NW + (q << 2)) * STR + cp;
                if (xok && (unsigned)rg < (unsigned)HH) {
                    const float* sr = sp + (size_t)rg * WW;
                    const float4 v0 = *(const float4*)sr;
                    const float4 v1 = *(const float4*)(sr + HW);
                    d[0 * STR] = as_u32(pk(v0.x, v1.x));
                    d[1 * STR] = as_u32(pk(v0.y, v1.y));
                    d[2 * STR] = as_u32(pk(v0.z, v1.z));
                    d[3 * STR] = as_u32(pk(v0.w, v1.w));
                } else {
                    d[0 * STR] = 0u; d[1 * STR] = 0u;
                    d[2 * STR] = 0u; d[3 * STR] = 0u;
                }
            }
        } else {
            // P: 4y x 8 quads x 8 cp = 256 tasks, 128 thr x 2
            const int t  = tid - 384;
            const int cp = t & 7;
            const int v  = t >> 3;           // 0..15
            const int y  = v & 3;
            const int qb = v >> 2;           // 0..3
            const float* sp = prv + ((size_t)(b * CC + c0 + 2 * cp) * HH + (y0 + y)) * WW + x0;
            #pragma unroll
            for (int it = 0; it < 2; ++it) {
                const int q  = qb + (it << 2);   // 0..7
                const int xq = q << 2;
                const float4 v0 = *(const float4*)(sp + xq);
                const float4 v1 = *(const float4*)(sp + xq + HW);
                unsigned* d = L + POFF + (y * XT + xq) * STR + cp;
                d[0 * STR] = as_u32(pk(v0.x, v1.x));
                d[1 * STR] = as_u32(pk(v0.y, v1.y));
                d[2 * STR] = as_u32(pk(v0.z, v1.z));
                d[3 * STR] = as_u32(pk(v0.w, v1.w));
            }
        }
    };

    // ---- compute: 18 MFMAs per wave per chunk ----
    auto compute = [&](int buf) {
        const unsigned* L = lds[buf];
        const h4 a0 = as_h4(*(const uint2*)(L + POFF + (((2 * y2 + 0) * XT) + (s << 4) + li) * STR + koff));
        const h4 a1 = as_h4(*(const uint2*)(L + POFF + (((2 * y2 + 1) * XT) + (s << 4) + li) * STR + koff));
        const unsigned* NB = L + NOFF + ((ts << 4) + li) * STR + koff;
        h4 bprev = as_h4(*(const uint2*)(NB + (2 * y2) * (NW * STR)));
        #pragma unroll
        for (int dy = 0; dy < ND; ++dy) {
            const h4 bnext = as_h4(*(const uint2*)(NB + (2 * y2 + dy + 1) * (NW * STR)));
            acc0[dy] = __builtin_amdgcn_mfma_f32_16x16x16f16(a0, bprev, acc0[dy], 0, 0, 0);
            acc1[dy] = __builtin_amdgcn_mfma_f32_16x16x16f16(a1, bnext, acc1[dy], 0, 0, 0);
            bprev = bnext;
        }
    };

    stage(0, 0);
    __syncthreads();
    for (int ck = 0; ck < 8; ++ck) {
        if (ck < 7) stage((ck + 1) & 1, ck + 1);
        compute(ck & 1);
        __syncthreads();
    }

    // ---- epilogue: scatter -> LDS, then coalesced float4 stores ----
    float* Ol = (float*)lds;                  // 81*4*32 f32 = 41472 B < 56320
    const float invc = 1.0f / (float)CC;
    #pragma unroll
    for (int dy = 0; dy < ND; ++dy) {
        #pragma unroll
        for (int r = 0; r < 4; ++r) {
            const int m  = (kg << 2) + r;
            const int px = (s << 4) + m;
            const int dx = (g << 4) + li - m - SR;
            if ((unsigned)dx < 9u) {
                const int comb = dy * ND + dx;
                Ol[((comb << 2) + (y2 << 1) + 0) * XT + px] = acc0[dy][r] * invc;
                Ol[((comb << 2) + (y2 << 1) + 1) * XT + px] = acc1[dy][r] * invc;
            }
        }
    }
    __syncthreads();
    #pragma unroll
    for (int it = 0; it < 6; ++it) {
        const int c = tid + (it << 9);
        if (c < (81 * YT * XT) / 4) {          // 2592 float4 chunks
            const int px4  = c & 7;
            const int y    = (c >> 3) & 3;
            const int comb = c >> 5;
            const float4 v = *(const float4*)&Ol[c << 2];
            *(float4*)(out + ((size_t)(b * 81 + comb) * HH + (y0 + y)) * WW + x0 + (px4 << 2)) = v;
        }
    }
}

extern "C" void kernel_launch(void* const* d_in, const int* in_sizes, int n_in,
                              void* d_out, int out_size, void* d_ws, size_t ws_size,
                              hipStream_t stream) {
    const float* prv = (const float*)d_in[0];
    const float* nxt = (const float*)d_in[1];
    float* out = (float*)d_out;

    const int nblocks = BB * (HH / YT) * (WW / XT);  // 4 * 32 * 8 = 1024
    costvol_kernel<<<nblocks, 512, 0, stream>>>(prv, nxt, out);
}